// Round 10
// baseline (1719.941 us; speedup 1.0000x reference)
//
#include <hip/hip_runtime.h>

typedef unsigned long long u64;
typedef unsigned int u32;
typedef unsigned char u8;
typedef int  v4i __attribute__((ext_vector_type(4)));
typedef unsigned int v4u __attribute__((ext_vector_type(4)));

#define TBL_BITS 18
#define TBL_SIZE (1u << TBL_BITS)
#define TBL_MASK (TBL_SIZE - 1u)
#define EMPTY_KEY 0xFFFFFFFFFFFFFFFFull

#define BK_BITS 9                 // 512-node buckets
#define BK_SZ   512
#define MAXNB   256
#define PBLK    2048              // partition blocks
#define LDSE    3200              // max edges per partition block
#define NSUB    5                 // nb sub-blocks per bucket (196*5=980 jobs)
#define GSTR    16                // gcur stride in u32 (64B per bucket line)
#define GRID_G  1024              // coop grid: 4 blocks/CU on 256 CUs

__device__ __forceinline__ u64 splitmix64(u64 z) {
    z = z + 0x9E3779B97F4A7C15ull;
    z = (z ^ (z >> 30)) * 0xBF58476D1CE4E5B9ull;
    z = (z ^ (z >> 27)) * 0x94D049BB133111EBull;
    return z ^ (z >> 31);
}

__device__ __forceinline__ v4i nt_load4(const int* p) {
    return __builtin_nontemporal_load((const v4i*)p);
}
__device__ __forceinline__ v4u nt_loadu4(const u32* p) {
    return __builtin_nontemporal_load((const v4u*)p);
}

// Sense-reversing grid barrier. All GRID_G blocks are co-resident by
// __launch_bounds__ construction, so spinning cannot deadlock. Device-scope
// atomics + __threadfence give release/acquire across XCDs.
__device__ __forceinline__ void grid_sync(u32* cnt, u32* gen) {
    __syncthreads();
    if (threadIdx.x == 0) {
        __threadfence();                         // release prior writes
        u32 g = atomicAdd(gen, 0u);
        if (atomicAdd(cnt, 1u) == (u32)gridDim.x - 1u) {
            atomicExch(cnt, 0u);
            __threadfence();
            atomicAdd(gen, 1u);
        } else {
            while (atomicAdd(gen, 0u) == g) { __builtin_amdgcn_s_sleep(4); }
        }
        __threadfence();                         // acquire (L2 invalidate)
    }
    __syncthreads();
}

// ---------------- one-pass fused edge partition (unchanged logic, gcur padded) ----------------
__global__ __launch_bounds__(256) void partition_kernel(const int* __restrict__ src,
                                                        const int* __restrict__ dst,
                                                        u32* __restrict__ gcur,
                                                        u32* __restrict__ packed,
                                                        int mI4, int nbuck, int cap, int per) {
    __shared__ u32 pk[LDSE];
    __shared__ u32 spk[LDSE];
    __shared__ u8  bd[LDSE];
    __shared__ u8  sbd[LDSE];
    __shared__ u32 hist[256], adjB[256], cur[256];
    __shared__ u32 wsum[4];
    int t = threadIdx.x, b = blockIdx.x;
    hist[t] = 0u;
    __syncthreads();
    int i0 = b * per;
    int i1 = i0 + per; if (i1 > mI4) i1 = mI4;
    int nI = i1 - i0; if (nI < 0) nI = 0;
    int nE = nI * 4;
    for (int i = t; i < nI; i += 256) {
        v4i dv = nt_load4(dst + 4 * (size_t)(i0 + i));
        v4i sv = nt_load4(src + 4 * (size_t)(i0 + i));
        u32 d, s, bid;
        d = (u32)dv.x; s = (u32)sv.x; bid = d >> BK_BITS;
        pk[4*i+0] = (s << BK_BITS) | (d & (BK_SZ-1u)); bd[4*i+0] = (u8)bid; atomicAdd(&hist[bid], 1u);
        d = (u32)dv.y; s = (u32)sv.y; bid = d >> BK_BITS;
        pk[4*i+1] = (s << BK_BITS) | (d & (BK_SZ-1u)); bd[4*i+1] = (u8)bid; atomicAdd(&hist[bid], 1u);
        d = (u32)dv.z; s = (u32)sv.z; bid = d >> BK_BITS;
        pk[4*i+2] = (s << BK_BITS) | (d & (BK_SZ-1u)); bd[4*i+2] = (u8)bid; atomicAdd(&hist[bid], 1u);
        d = (u32)dv.w; s = (u32)sv.w; bid = d >> BK_BITS;
        pk[4*i+3] = (s << BK_BITS) | (d & (BK_SZ-1u)); bd[4*i+3] = (u8)bid; atomicAdd(&hist[bid], 1u);
    }
    __syncthreads();
    u32 v = hist[t];
    int lane = t & 63, w = t >> 6;
    int x = (int)v;
    #pragma unroll
    for (int o = 1; o < 64; o <<= 1) {
        int y = __shfl_up(x, o);
        if (lane >= o) x += y;
    }
    if (lane == 63) wsum[w] = (u32)x;
    __syncthreads();
    u32 woff = 0;
    for (int ww = 0; ww < w; ++ww) woff += wsum[ww];
    u32 excl = woff + (u32)x - v;
    cur[t] = excl;
    if (t < nbuck && v > 0u) {
        u32 bpos = atomicAdd(&gcur[t * GSTR], v);
        if (bpos > (u32)cap - v) bpos = (u32)cap - v;   // clamp (statistically impossible)
        adjB[t] = (u32)t * (u32)cap + bpos - excl;
    }
    __syncthreads();
    for (int i = t; i < nE; i += 256) {
        u32 bb = (u32)bd[i];
        u32 p = atomicAdd(&cur[bb], 1u);
        spk[p] = pk[i];
        sbd[p] = (u8)bb;
    }
    __syncthreads();
    for (int p = t; p < nE; p += 256) {
        packed[adjB[sbd[p]] + (u32)p] = spk[p];
    }
}

// ---------------- cooperative mega-kernel: argmax + 3 WL iterations ----------------
__global__ __launch_bounds__(256, 4) void wl_coop(const float* __restrict__ x,
                                                  const u32* __restrict__ packed,
                                                  const u32* __restrict__ gcur,
                                                  u64* __restrict__ h,
                                                  u64* __restrict__ nbp, size_t nstride,
                                                  u64* __restrict__ keys, u32* __restrict__ vals,
                                                  u32* __restrict__ slotarr, u32* __restrict__ f,
                                                  u32* __restrict__ lrank, u32* __restrict__ partials,
                                                  u32* __restrict__ offsets,
                                                  u32* __restrict__ bcnt, u32* __restrict__ bgen,
                                                  int* __restrict__ out,
                                                  int n, int nbuck, int cap, int npb) {
    int t = threadIdx.x, b = blockIdx.x;
    __shared__ u64 sb64[512];
    u32* sb32 = (u32*)sb64;
    __shared__ u32 ws[8];

    // phase 0: argmax (one wave per row, grid-stride) -> out col 0, h
    {
        int wv = (b * 256 + t) >> 6, lane = t & 63;
        const int WPG = (GRID_G * 256) >> 6;
        for (int row = wv; row < n; row += WPG) {
            float v = x[(size_t)row * 64 + lane];
            int idx = lane;
            #pragma unroll
            for (int off = 32; off >= 1; off >>= 1) {
                float ov = __shfl_xor(v, off);
                int   oi = __shfl_xor(idx, off);
                if (ov > v || (ov == v && oi < idx)) { v = ov; idx = oi; }
            }
            if (lane == 0) {
                h[row] = splitmix64((u64)idx + 1ull);
                out[(size_t)row * 4 + 0] = idx;
            }
        }
    }
    grid_sync(bcnt, bgen);

    const int njobs = nbuck * NSUB;
    for (int it = 0; it < 3; ++it) {
        // P1: nb partial sums (blocks < njobs) || hash-table clear (rest)
        if (b < njobs) {
            int bucket = b / NSUB, sub = b - bucket * NSUB;
            sb64[t] = 0ull; sb64[t + 256] = 0ull;
            __syncthreads();
            u32 lo = (u32)bucket * (u32)cap;
            u32 len = gcur[bucket * GSTR];
            u32 q0 = ((len * (u32)sub) / NSUB) & ~3u;
            u32 q1 = (sub == NSUB - 1) ? len : (((len * (u32)(sub + 1)) / NSUB) & ~3u);
            u32 nv4 = (q1 - q0) >> 2;
            const u32* pbase = packed + lo + q0;
            for (u32 i = (u32)t; i < nv4; i += 256) {
                v4u vv = nt_loadu4(pbase + 4 * (size_t)i);
                atomicAdd(&sb64[vv.x & (BK_SZ - 1u)], h[vv.x >> BK_BITS]);
                atomicAdd(&sb64[vv.y & (BK_SZ - 1u)], h[vv.y >> BK_BITS]);
                atomicAdd(&sb64[vv.z & (BK_SZ - 1u)], h[vv.z >> BK_BITS]);
                atomicAdd(&sb64[vv.w & (BK_SZ - 1u)], h[vv.w >> BK_BITS]);
            }
            for (u32 e = q0 + nv4 * 4 + (u32)t; e < q1; e += 256) {
                u32 vv = packed[lo + e];
                atomicAdd(&sb64[vv & (BK_SZ - 1u)], h[vv >> BK_BITS]);
            }
            __syncthreads();
            u64* dp = nbp + (size_t)sub * nstride + ((size_t)bucket << BK_BITS);
            dp[t] = sb64[t];
            dp[t + 256] = sb64[t + 256];
        } else {
            int cb = b - njobs;
            u32 step = (u32)(GRID_G - njobs) * 256u;
            for (u32 s = (u32)cb * 256u + (u32)t; s < TBL_SIZE; s += step) {
                keys[s] = EMPTY_KEY;
                vals[s] = 0xFFFFFFFFu;
            }
        }
        grid_sync(bcnt, bgen);

        // P2: signatures + hash-table insert (read-before-CAS; slots write-once)
        for (int i = b * 256 + t; i < n; i += GRID_G * 256) {
            u64 nbv = 0;
            #pragma unroll
            for (int s2 = 0; s2 < NSUB; ++s2) nbv += nbp[(size_t)s2 * nstride + i];
            u64 sg = splitmix64(h[i] * 0x100000001B3ull + nbv);
            u32 slot = (u32)sg & TBL_MASK;
            while (true) {
                u64 k = keys[slot];
                if (k == sg) break;
                if (k == EMPTY_KEY) {
                    u64 prev = atomicCAS(&keys[slot], (u64)EMPTY_KEY, sg);
                    if (prev == EMPTY_KEY || prev == sg) break;
                }
                slot = (slot + 1u) & TBL_MASK;
            }
            atomicMin(&vals[slot], (u32)i);
            slotarr[i] = slot;
        }
        grid_sync(bcnt, bgen);

        // P3: first-occurrence lookup + per-256-chunk local rank + chunk totals
        if (b < npb) {
            int i = b * 256 + t;
            u32 isf = 0, fi = 0;
            if (i < n) {
                fi = vals[slotarr[i]];
                f[i] = fi;
                isf = (fi == (u32)i) ? 1u : 0u;
            }
            u32 lane = t & 63, wv = (u32)t >> 6;
            int xx = (int)isf;
            #pragma unroll
            for (int o = 1; o < 64; o <<= 1) {
                int y = __shfl_up(xx, o);
                if (lane >= (u32)o) xx += y;
            }
            if (lane == 63) ws[wv] = (u32)xx;
            __syncthreads();
            u32 woff = 0;
            for (u32 w2 = 0; w2 < wv; ++w2) woff += ws[w2];
            if (i < n) lrank[i] = woff + (u32)xx - isf;
            if (t == 255) partials[b] = woff + (u32)xx;
        }
        grid_sync(bcnt, bgen);

        // P4: redundant block-scan of chunk totals + relabel (grid-stride)
        {
            u32 e0 = (2 * t     < npb) ? partials[2 * t]     : 0u;
            u32 e1 = (2 * t + 1 < npb) ? partials[2 * t + 1] : 0u;
            u32 s = e0 + e1;
            int lane = t & 63, w = t >> 6;
            int xx = (int)s;
            #pragma unroll
            for (int o = 1; o < 64; o <<= 1) {
                int y = __shfl_up(xx, o);
                if (lane >= o) xx += y;
            }
            if (lane == 63) ws[w] = (u32)xx;
            __syncthreads();
            u32 woff = 0;
            for (int w2 = 0; w2 < w; ++w2) woff += ws[w2];
            u32 incl = woff + (u32)xx;
            u32 excl = incl - s;
            sb32[2 * t]     = excl;
            sb32[2 * t + 1] = excl + e0;
            __syncthreads();
            u32 base = offsets[it];
            if (b == 0 && t == 0) offsets[it + 1] = base + ws[0] + ws[1] + ws[2] + ws[3];
            for (int i = b * 256 + t; i < n; i += GRID_G * 256) {
                u32 j = f[i];
                u32 c = base + sb32[j >> 8] + lrank[j];
                h[i] = splitmix64((u64)c + 1ull);
                out[(size_t)i * 4 + (it + 1)] = (int)c;
            }
        }
        grid_sync(bcnt, bgen);
    }
}

// ---------------- fallback path (proven, split kernels) ----------------

__global__ void argmax_kernel(const float* __restrict__ x, u64* __restrict__ h,
                              int* __restrict__ out, u32* __restrict__ offsets, int n) {
    if (blockIdx.x == 0 && threadIdx.x == 0) offsets[0] = 0u;
    int wave = (int)((blockIdx.x * (u32)blockDim.x + threadIdx.x) >> 6);
    int lane = threadIdx.x & 63;
    if (wave >= n) return;
    float v = x[(size_t)wave * 64 + lane];
    int idx = lane;
    #pragma unroll
    for (int off = 32; off >= 1; off >>= 1) {
        float ov = __shfl_xor(v, off);
        int   oi = __shfl_xor(idx, off);
        if (ov > v || (ov == v && oi < idx)) { v = ov; idx = oi; }
    }
    if (lane == 0) {
        h[wave] = splitmix64((u64)idx + 1ull);
        out[(size_t)wave * 4 + 0] = idx;
    }
}

__global__ void init_iter_kernel(u64* __restrict__ keys, u32* __restrict__ vals,
                                 u64* __restrict__ nb, int n) {
    int i = blockIdx.x * blockDim.x + threadIdx.x;
    if (i < (int)TBL_SIZE) { keys[i] = EMPTY_KEY; vals[i] = 0xFFFFFFFFu; }
    if (i < n) nb[i] = 0ull;
}

__global__ void edge_kernel(const int* __restrict__ src, const int* __restrict__ dst,
                            const u64* __restrict__ h, u64* __restrict__ nb, int m) {
    int stride = gridDim.x * blockDim.x;
    for (int e = blockIdx.x * blockDim.x + threadIdx.x; e < m; e += stride) {
        atomicAdd(&nb[(u32)dst[e]], h[(u32)src[e]]);
    }
}

__global__ void sig_kernel1(const u64* __restrict__ h, const u64* __restrict__ nb,
                            u32* __restrict__ slotarr, u64* __restrict__ keys,
                            u32* __restrict__ vals, int n) {
    int i = blockIdx.x * blockDim.x + threadIdx.x;
    if (i >= n) return;
    u64 sg = splitmix64(h[i] * 0x100000001B3ull + nb[i]);
    u32 slot = (u32)sg & TBL_MASK;
    while (true) {
        u64 k = keys[slot];
        if (k == sg) break;
        if (k == EMPTY_KEY) {
            u64 prev = atomicCAS(&keys[slot], (u64)EMPTY_KEY, sg);
            if (prev == EMPTY_KEY || prev == sg) break;
        }
        slot = (slot + 1u) & TBL_MASK;
    }
    atomicMin(&vals[slot], (u32)i);
    slotarr[i] = slot;
}

__global__ void count_rank(const u32* __restrict__ slotarr, const u32* __restrict__ vals,
                           u32* __restrict__ f, u32* __restrict__ lrank,
                           u32* __restrict__ partials, int n) {
    int b = blockIdx.x, t = threadIdx.x;
    int i = b * 256 + t;
    u32 isf = 0, fi = 0;
    if (i < n) {
        fi = vals[slotarr[i]];
        f[i] = fi;
        isf = (fi == (u32)i) ? 1u : 0u;
    }
    __shared__ u32 wsum[4];
    u32 lane = t & 63, wv = (u32)t >> 6;
    int x = (int)isf;
    #pragma unroll
    for (int o = 1; o < 64; o <<= 1) {
        int y = __shfl_up(x, o);
        if (lane >= (u32)o) x += y;
    }
    if (lane == 63) wsum[wv] = (u32)x;
    __syncthreads();
    u32 woff = 0;
    for (u32 w = 0; w < wv; ++w) woff += wsum[w];
    if (i < n) lrank[i] = woff + (u32)x - isf;
    if (t == 255) partials[b] = woff + (u32)x;
}

__global__ __launch_bounds__(512) void relabel_fused(const u32* __restrict__ f,
                                                     const u32* __restrict__ lrank,
                                                     const u32* __restrict__ partials,
                                                     u32* __restrict__ offsets, int iter,
                                                     u64* __restrict__ h, int* __restrict__ out,
                                                     int n, int npb) {
    __shared__ u32 pp[512];
    __shared__ u32 ws[8];
    int t = threadIdx.x;
    u32 v = (t < npb) ? partials[t] : 0u;
    int lane = t & 63, w = t >> 6;
    int x = (int)v;
    #pragma unroll
    for (int o = 1; o < 64; o <<= 1) {
        int y = __shfl_up(x, o);
        if (lane >= o) x += y;
    }
    if (lane == 63) ws[w] = (u32)x;
    __syncthreads();
    u32 woff = 0;
    for (int ww = 0; ww < w; ++ww) woff += ws[ww];
    u32 incl = woff + (u32)x;
    pp[t] = incl - v;
    if (blockIdx.x == 0 && t == 511) offsets[iter + 1] = offsets[iter] + incl;
    __syncthreads();
    int i = blockIdx.x * 512 + t;
    if (i >= n) return;
    u32 j = f[i];
    u32 c = offsets[iter] + pp[j >> 8] + lrank[j];
    h[i] = splitmix64((u64)c + 1ull);
    out[(size_t)i * 4 + (iter + 1)] = (int)c;
}

extern "C" void kernel_launch(void* const* d_in, const int* in_sizes, int n_in,
                              void* d_out, int out_size, void* d_ws, size_t ws_size,
                              hipStream_t stream) {
    const float* x = (const float*)d_in[0];
    const int* ei = (const int*)d_in[1];     // int32 on device
    int n = in_sizes[0] / 64;
    int m = in_sizes[1] / 2;
    const int* src = ei;
    const int* dst = ei + m;
    int* out = (int*)d_out;

    const int NPB = (n + 255) / 256;
    const int NRB = (n + 511) / 512;
    const int nbuck = (n + BK_SZ - 1) >> BK_BITS;
    const size_t nstride = (size_t)nbuck << BK_BITS;
    const int mI4 = m >> 2;
    const int per = (mI4 + PBLK - 1) / PBLK;
    const int cap = (int)((((size_t)m / (size_t)(nbuck > 0 ? nbuck : 1)) * 9 / 8 + 2048 + 255) & ~(size_t)255);

    auto align = [](size_t v) { return (v + 255) & ~(size_t)255; };
    const size_t meta_bytes = ((size_t)(256 * GSTR) + 16) * 4;   // gcur + offsets/bcnt/bgen
    size_t sz_meta   = align(meta_bytes);
    size_t sz_packed = align((size_t)nbuck * (size_t)cap * 4);
    size_t sz_h      = align((size_t)n * 8);
    size_t sz_nbp    = align(nstride * 8 * NSUB);
    size_t sz_tblk   = align((size_t)TBL_SIZE * 8);
    size_t sz_tblv   = align((size_t)TBL_SIZE * 4);
    size_t sz_n4     = align((size_t)n * 4);
    size_t sz_small  = align((size_t)512 * 4);
    size_t need_fast = sz_meta + sz_packed + sz_h + sz_nbp + sz_tblk + sz_tblv
                     + 3 * sz_n4 + sz_small + 256;

    char* p = (char*)d_ws;
    bool fast = (ws_size >= need_fast) && (nbuck <= MAXNB) && ((m & 3) == 0)
              && (NPB <= 512) && (per * 4 <= LDSE) && (n >= 256)
              && (nbuck * NSUB + 1 <= GRID_G);
    if (fast) {
        u32* meta    = (u32*)p; p += sz_meta;
        u32* gcur    = meta;                      // 256*GSTR u32
        u32* offsets = meta + 256 * GSTR;         // 8 u32
        u32* bcnt    = meta + 256 * GSTR + 8;
        u32* bgen    = meta + 256 * GSTR + 9;
        u32* packed  = (u32*)p; p += sz_packed;
        u64* h       = (u64*)p; p += sz_h;
        u64* nbp     = (u64*)p; p += sz_nbp;
        u64* keys    = (u64*)p; p += sz_tblk;
        u32* vals    = (u32*)p; p += sz_tblv;
        u32* slotarr = (u32*)p; p += sz_n4;
        u32* f       = (u32*)p; p += sz_n4;
        u32* lrank   = (u32*)p; p += sz_n4;
        u32* partials= (u32*)p;

        hipMemsetAsync(d_ws, 0, meta_bytes, stream);
        partition_kernel<<<PBLK, 256, 0, stream>>>(src, dst, gcur, packed, mI4, nbuck, cap, per);
        wl_coop<<<GRID_G, 256, 0, stream>>>(x, packed, gcur, h, nbp, nstride, keys, vals,
                                            slotarr, f, lrank, partials, offsets,
                                            bcnt, bgen, out, n, nbuck, cap, NPB);
    } else {
        u64* h       = (u64*)p; p += sz_h;
        u64* nb      = (u64*)p; p += sz_h;
        u64* keys    = (u64*)p; p += sz_tblk;
        u32* vals    = (u32*)p; p += sz_tblv;
        u32* slotarr = (u32*)p; p += sz_n4;
        u32* f       = (u32*)p; p += sz_n4;
        u32* lrank   = (u32*)p; p += sz_n4;
        u32* partials= (u32*)p; p += sz_small;
        u32* offsets = (u32*)p;

        argmax_kernel<<<(n + 3) / 4, 256, 0, stream>>>(x, h, out, offsets, n);
        for (int it = 0; it < 3; ++it) {
            init_iter_kernel<<<(TBL_SIZE + 255) / 256, 256, 0, stream>>>(keys, vals, nb, n);
            edge_kernel  <<<4096, 256, 0, stream>>>(src, dst, h, nb, m);
            sig_kernel1  <<<NPB, 256, 0, stream>>>(h, nb, slotarr, keys, vals, n);
            count_rank   <<<NPB, 256, 0, stream>>>(slotarr, vals, f, lrank, partials, n);
            relabel_fused<<<NRB, 512, 0, stream>>>(f, lrank, partials, offsets, it, h, out, n, NPB);
        }
    }
}

// Round 11
// 266.115 us; speedup vs baseline: 6.4632x; 6.4632x over previous
//
#include <hip/hip_runtime.h>

typedef unsigned long long u64;
typedef unsigned int u32;
typedef unsigned char u8;
typedef int  v4i __attribute__((ext_vector_type(4)));
typedef unsigned int v4u __attribute__((ext_vector_type(4)));

#define TBL_BITS 18
#define TBL_SIZE (1u << TBL_BITS)
#define TBL_MASK (TBL_SIZE - 1u)
#define EMPTY_KEY 0xFFFFFFFFFFFFFFFFull

#define BK_BITS 9                 // 512-node buckets
#define BK_SZ   512
#define MAXNB   256
#define PBLK    2048              // partition blocks
#define LDSE    3200              // max edges per partition block
#define NSUB    8                 // nb sub-blocks per bucket
#define GSTR    16                // gcur stride in u32 (64B per bucket line)

__device__ __forceinline__ u64 splitmix64(u64 z) {
    z = z + 0x9E3779B97F4A7C15ull;
    z = (z ^ (z >> 30)) * 0xBF58476D1CE4E5B9ull;
    z = (z ^ (z >> 27)) * 0x94D049BB133111EBull;
    return z ^ (z >> 31);
}

__device__ __forceinline__ v4i nt_load4(const int* p) {
    return __builtin_nontemporal_load((const v4i*)p);
}
__device__ __forceinline__ v4u nt_loadu4(const u32* p) {
    return __builtin_nontemporal_load((const v4u*)p);
}

// ---------------- fused: argmax prologue + one-pass edge partition ----------------
// Prologue: one wave per row (grid-stride) argmax -> out col 0, h.
// Partition: cache edge chunk in LDS -> LDS histogram -> one global atomicAdd
// per non-empty bucket (allocates contiguous sub-region in the bucket's fixed-
// capacity region) -> LDS counting sort -> bucket-contiguous global stores.
// Region order nondeterministic; downstream sums commutative -> output exact.
__global__ __launch_bounds__(256) void partition_argmax(const float* __restrict__ x,
                                                        const int* __restrict__ src,
                                                        const int* __restrict__ dst,
                                                        u32* __restrict__ gcur,
                                                        u32* __restrict__ packed,
                                                        u64* __restrict__ h,
                                                        int* __restrict__ out,
                                                        int n, int mI4, int nbuck, int cap, int per) {
    int t = threadIdx.x, b = blockIdx.x;
    // ---- argmax prologue (no LDS) ----
    {
        int wv = (b * 256 + t) >> 6, lane = t & 63;
        const int WPG = (PBLK * 256) >> 6;
        for (int row = wv; row < n; row += WPG) {
            float v = x[(size_t)row * 64 + lane];
            int idx = lane;
            #pragma unroll
            for (int off = 32; off >= 1; off >>= 1) {
                float ov = __shfl_xor(v, off);
                int   oi = __shfl_xor(idx, off);
                if (ov > v || (ov == v && oi < idx)) { v = ov; idx = oi; }
            }
            if (lane == 0) {
                h[row] = splitmix64((u64)idx + 1ull);
                out[(size_t)row * 4 + 0] = idx;
            }
        }
    }
    // ---- partition ----
    __shared__ u32 pk[LDSE];
    __shared__ u32 spk[LDSE];
    __shared__ u8  bd[LDSE];
    __shared__ u8  sbd[LDSE];
    __shared__ u32 hist[256], adjB[256], cur[256];
    __shared__ u32 wsum[4];
    hist[t] = 0u;
    __syncthreads();
    int i0 = b * per;
    int i1 = i0 + per; if (i1 > mI4) i1 = mI4;
    int nI = i1 - i0; if (nI < 0) nI = 0;
    int nE = nI * 4;
    for (int i = t; i < nI; i += 256) {
        v4i dv = nt_load4(dst + 4 * (size_t)(i0 + i));
        v4i sv = nt_load4(src + 4 * (size_t)(i0 + i));
        u32 d, s, bid;
        d = (u32)dv.x; s = (u32)sv.x; bid = d >> BK_BITS;
        pk[4*i+0] = (s << BK_BITS) | (d & (BK_SZ-1u)); bd[4*i+0] = (u8)bid; atomicAdd(&hist[bid], 1u);
        d = (u32)dv.y; s = (u32)sv.y; bid = d >> BK_BITS;
        pk[4*i+1] = (s << BK_BITS) | (d & (BK_SZ-1u)); bd[4*i+1] = (u8)bid; atomicAdd(&hist[bid], 1u);
        d = (u32)dv.z; s = (u32)sv.z; bid = d >> BK_BITS;
        pk[4*i+2] = (s << BK_BITS) | (d & (BK_SZ-1u)); bd[4*i+2] = (u8)bid; atomicAdd(&hist[bid], 1u);
        d = (u32)dv.w; s = (u32)sv.w; bid = d >> BK_BITS;
        pk[4*i+3] = (s << BK_BITS) | (d & (BK_SZ-1u)); bd[4*i+3] = (u8)bid; atomicAdd(&hist[bid], 1u);
    }
    __syncthreads();
    u32 v = hist[t];
    int lane = t & 63, w = t >> 6;
    int x2 = (int)v;
    #pragma unroll
    for (int o = 1; o < 64; o <<= 1) {
        int y = __shfl_up(x2, o);
        if (lane >= o) x2 += y;
    }
    if (lane == 63) wsum[w] = (u32)x2;
    __syncthreads();
    u32 woff = 0;
    for (int ww = 0; ww < w; ++ww) woff += wsum[ww];
    u32 excl = woff + (u32)x2 - v;
    cur[t] = excl;
    if (t < nbuck && v > 0u) {
        u32 bpos = atomicAdd(&gcur[t * GSTR], v);
        if (bpos > (u32)cap - v) bpos = (u32)cap - v;   // clamp (statistically impossible)
        adjB[t] = (u32)t * (u32)cap + bpos - excl;
    }
    __syncthreads();
    for (int i = t; i < nE; i += 256) {
        u32 bb = (u32)bd[i];
        u32 p = atomicAdd(&cur[bb], 1u);
        spk[p] = pk[i];
        sbd[p] = (u8)bb;
    }
    __syncthreads();
    for (int p = t; p < nE; p += 256) {
        packed[adjB[sbd[p]] + (u32)p] = spk[p];
    }
}

// Blocks [0, nbuck*NSUB): sub-block s of bucket b accumulates its 1/NSUB of
// the bucket's edges into 512 u64 LDS accumulators, then OVERWRITES its slice
// of partial array nb8[s]. Blocks [nbuck*NSUB, +256): clear the hash table.
__global__ __launch_bounds__(256) void nb_kernel(const u32* __restrict__ packed,
                                                 const u32* __restrict__ gcur,
                                                 const u64* __restrict__ h,
                                                 u64* __restrict__ nb8, size_t nstride,
                                                 u64* __restrict__ keys,
                                                 u32* __restrict__ vals, int nbuck, int cap) {
    int b = blockIdx.x, t = threadIdx.x;
    if (b >= nbuck * NSUB) {
        int base = (b - nbuck * NSUB) * 1024;
        for (int k = t; k < 1024; k += 256) { keys[base + k] = EMPTY_KEY; vals[base + k] = 0xFFFFFFFFu; }
        return;
    }
    int bucket = b >> 3, sub = b & 7;
    __shared__ u64 acc[BK_SZ];
    acc[t] = 0ull; acc[t + 256] = 0ull;
    __syncthreads();
    u32 lo = (u32)bucket * (u32)cap;               // cap multiple of 4 -> 16B aligned
    u32 len = gcur[bucket * GSTR];
    u32 q0 = ((len * (u32)sub) >> 3) & ~3u;
    u32 q1 = (sub == 7) ? len : (((len * (u32)(sub + 1)) >> 3) & ~3u);
    u32 nv4 = (q1 - q0) >> 2;
    const u32* pbase = packed + lo + q0;
    for (u32 i = (u32)t; i < nv4; i += 256) {
        v4u vv = nt_loadu4(pbase + 4 * (size_t)i);
        atomicAdd(&acc[vv.x & (BK_SZ - 1u)], h[vv.x >> BK_BITS]);
        atomicAdd(&acc[vv.y & (BK_SZ - 1u)], h[vv.y >> BK_BITS]);
        atomicAdd(&acc[vv.z & (BK_SZ - 1u)], h[vv.z >> BK_BITS]);
        atomicAdd(&acc[vv.w & (BK_SZ - 1u)], h[vv.w >> BK_BITS]);
    }
    for (u32 e = q0 + nv4 * 4 + (u32)t; e < q1; e += 256) {
        u32 vv = packed[lo + e];
        atomicAdd(&acc[vv & (BK_SZ - 1u)], h[vv >> BK_BITS]);
    }
    __syncthreads();
    u64* dstp = nb8 + (size_t)sub * nstride + ((size_t)bucket << BK_BITS);
    dstp[t] = acc[t];
    dstp[t + 256] = acc[t + 256];
}

// sig = splitmix64(h*FNV + sum of NSUB nb partials); read-before-CAS insert;
// first occurrence via atomicMin (order-independent). Slots are write-once
// EMPTY->key, so a stale plain read yields EMPTY or the final key -> safe.
__global__ void sig_kernel8(const u64* __restrict__ h, const u64* __restrict__ nb8,
                            size_t nstride, u32* __restrict__ slotarr,
                            u64* __restrict__ keys, u32* __restrict__ vals, int n) {
    int i = blockIdx.x * blockDim.x + threadIdx.x;
    if (i >= n) return;
    u64 nbv = 0;
    #pragma unroll
    for (int s = 0; s < NSUB; ++s) nbv += nb8[(size_t)s * nstride + i];
    u64 sg = splitmix64(h[i] * 0x100000001B3ull + nbv);
    u32 slot = (u32)sg & TBL_MASK;
    while (true) {
        u64 k = keys[slot];
        if (k == sg) break;
        if (k == EMPTY_KEY) {
            u64 prev = atomicCAS(&keys[slot], (u64)EMPTY_KEY, sg);
            if (prev == EMPTY_KEY || prev == sg) break;
        }
        slot = (slot + 1u) & TBL_MASK;
    }
    atomicMin(&vals[slot], (u32)i);
    slotarr[i] = slot;
}

__global__ void sig_kernel1(const u64* __restrict__ h, const u64* __restrict__ nb,
                            u32* __restrict__ slotarr, u64* __restrict__ keys,
                            u32* __restrict__ vals, int n) {
    int i = blockIdx.x * blockDim.x + threadIdx.x;
    if (i >= n) return;
    u64 sg = splitmix64(h[i] * 0x100000001B3ull + nb[i]);
    u32 slot = (u32)sg & TBL_MASK;
    while (true) {
        u64 k = keys[slot];
        if (k == sg) break;
        if (k == EMPTY_KEY) {
            u64 prev = atomicCAS(&keys[slot], (u64)EMPTY_KEY, sg);
            if (prev == EMPTY_KEY || prev == sg) break;
        }
        slot = (slot + 1u) & TBL_MASK;
    }
    atomicMin(&vals[slot], (u32)i);
    slotarr[i] = slot;
}

// f[i] = first-occurrence index; per-256-chunk exclusive rank; chunk totals.
__global__ void count_rank(const u32* __restrict__ slotarr, const u32* __restrict__ vals,
                           u32* __restrict__ f, u32* __restrict__ lrank,
                           u32* __restrict__ partials, int n) {
    int b = blockIdx.x, t = threadIdx.x;
    int i = b * 256 + t;
    u32 isf = 0, fi = 0;
    if (i < n) {
        fi = vals[slotarr[i]];
        f[i] = fi;
        isf = (fi == (u32)i) ? 1u : 0u;
    }
    __shared__ u32 wsum[4];
    u32 lane = t & 63, wv = (u32)t >> 6;
    int x = (int)isf;
    #pragma unroll
    for (int o = 1; o < 64; o <<= 1) {
        int y = __shfl_up(x, o);
        if (lane >= (u32)o) x += y;
    }
    if (lane == 63) wsum[wv] = (u32)x;
    __syncthreads();
    u32 woff = 0;
    for (u32 w = 0; w < wv; ++w) woff += wsum[w];
    if (i < n) lrank[i] = woff + (u32)x - isf;
    if (t == 255) partials[b] = woff + (u32)x;
}

// Fused: every block redundantly block-scans the per-chunk partials in LDS,
// then relabels 512 nodes: color = offset + pp[chunk(f)] + lrank[f].
// Block 0 also advances the persistent color counter.
__global__ __launch_bounds__(512) void relabel_fused(const u32* __restrict__ f,
                                                     const u32* __restrict__ lrank,
                                                     const u32* __restrict__ partials,
                                                     u32* __restrict__ offsets, int iter,
                                                     u64* __restrict__ h, int* __restrict__ out,
                                                     int n, int npb) {
    __shared__ u32 pp[512];
    __shared__ u32 ws[8];
    int t = threadIdx.x;
    u32 v = (t < npb) ? partials[t] : 0u;
    int lane = t & 63, w = t >> 6;
    int x = (int)v;
    #pragma unroll
    for (int o = 1; o < 64; o <<= 1) {
        int y = __shfl_up(x, o);
        if (lane >= o) x += y;
    }
    if (lane == 63) ws[w] = (u32)x;
    __syncthreads();
    u32 woff = 0;
    for (int ww = 0; ww < w; ++ww) woff += ws[ww];
    u32 incl = woff + (u32)x;
    pp[t] = incl - v;                       // exclusive prefix
    if (blockIdx.x == 0 && t == 511) offsets[iter + 1] = offsets[iter] + incl;
    __syncthreads();
    int i = blockIdx.x * 512 + t;
    if (i >= n) return;
    u32 j = f[i];
    u32 c = offsets[iter] + pp[j >> 8] + lrank[j];
    h[i] = splitmix64((u64)c + 1ull);
    out[(size_t)i * 4 + (iter + 1)] = (int)c;
}

// ---------------- fallback path (proven) ----------------

__global__ void argmax_kernel(const float* __restrict__ x, u64* __restrict__ h,
                              int* __restrict__ out, u32* __restrict__ offsets, int n) {
    if (blockIdx.x == 0 && threadIdx.x == 0) offsets[0] = 0u;
    int wave = (int)((blockIdx.x * (u32)blockDim.x + threadIdx.x) >> 6);
    int lane = threadIdx.x & 63;
    if (wave >= n) return;
    float v = x[(size_t)wave * 64 + lane];
    int idx = lane;
    #pragma unroll
    for (int off = 32; off >= 1; off >>= 1) {
        float ov = __shfl_xor(v, off);
        int   oi = __shfl_xor(idx, off);
        if (ov > v || (ov == v && oi < idx)) { v = ov; idx = oi; }
    }
    if (lane == 0) {
        h[wave] = splitmix64((u64)idx + 1ull);
        out[(size_t)wave * 4 + 0] = idx;
    }
}

__global__ void init_iter_kernel(u64* __restrict__ keys, u32* __restrict__ vals,
                                 u64* __restrict__ nb, int n) {
    int i = blockIdx.x * blockDim.x + threadIdx.x;
    if (i < (int)TBL_SIZE) { keys[i] = EMPTY_KEY; vals[i] = 0xFFFFFFFFu; }
    if (i < n) nb[i] = 0ull;
}

__global__ void edge_kernel(const int* __restrict__ src, const int* __restrict__ dst,
                            const u64* __restrict__ h, u64* __restrict__ nb, int m) {
    int stride = gridDim.x * blockDim.x;
    for (int e = blockIdx.x * blockDim.x + threadIdx.x; e < m; e += stride) {
        atomicAdd(&nb[(u32)dst[e]], h[(u32)src[e]]);
    }
}

extern "C" void kernel_launch(void* const* d_in, const int* in_sizes, int n_in,
                              void* d_out, int out_size, void* d_ws, size_t ws_size,
                              hipStream_t stream) {
    const float* x = (const float*)d_in[0];
    const int* ei = (const int*)d_in[1];     // int32 on device
    int n = in_sizes[0] / 64;
    int m = in_sizes[1] / 2;
    const int* src = ei;
    const int* dst = ei + m;
    int* out = (int*)d_out;

    const int NPB = (n + 255) / 256;
    const int NRB = (n + 511) / 512;
    const int nbuck = (n + BK_SZ - 1) >> BK_BITS;
    const size_t nstride = (size_t)nbuck << BK_BITS;
    const int mI4 = m >> 2;
    const int per = (mI4 + PBLK - 1) / PBLK;
    const int cap = (int)((((size_t)m / (size_t)(nbuck > 0 ? nbuck : 1)) * 9 / 8 + 2048 + 255) & ~(size_t)255);

    auto align = [](size_t v) { return (v + 255) & ~(size_t)255; };
    const size_t meta_bytes = ((size_t)(MAXNB * GSTR) + 16) * 4;   // gcur + offsets
    size_t sz_meta   = align(meta_bytes);
    size_t sz_packed = align((size_t)nbuck * (size_t)cap * 4);
    size_t sz_h      = align((size_t)n * 8);
    size_t sz_nbp    = align(nstride * 8 * NSUB);
    size_t sz_tblk   = align((size_t)TBL_SIZE * 8);
    size_t sz_tblv   = align((size_t)TBL_SIZE * 4);
    size_t sz_n4     = align((size_t)n * 4);
    size_t sz_small  = align((size_t)512 * 4);
    size_t need_fast = sz_meta + sz_packed + sz_h + sz_nbp + sz_tblk + sz_tblv
                     + 3 * sz_n4 + sz_small + 256;

    char* p = (char*)d_ws;
    bool fast = (ws_size >= need_fast) && (nbuck <= MAXNB) && ((m & 3) == 0)
              && (NPB <= 512) && (per * 4 <= LDSE) && (n >= 256);
    if (fast) {
        u32* meta    = (u32*)p; p += sz_meta;
        u32* gcur    = meta;                      // MAXNB*GSTR u32 (zeroed)
        u32* offsets = meta + MAXNB * GSTR;       // 16 u32 (offsets[0]=0 via memset)
        u32* packed  = (u32*)p; p += sz_packed;
        u64* h       = (u64*)p; p += sz_h;
        u64* nbp     = (u64*)p; p += sz_nbp;
        u64* keys    = (u64*)p; p += sz_tblk;
        u32* vals    = (u32*)p; p += sz_tblv;
        u32* slotarr = (u32*)p; p += sz_n4;
        u32* f       = (u32*)p; p += sz_n4;
        u32* lrank   = (u32*)p; p += sz_n4;
        u32* partials= (u32*)p;

        hipMemsetAsync(d_ws, 0, meta_bytes, stream);
        partition_argmax<<<PBLK, 256, 0, stream>>>(x, src, dst, gcur, packed, h, out,
                                                   n, mI4, nbuck, cap, per);
        for (int it = 0; it < 3; ++it) {
            nb_kernel    <<<nbuck * NSUB + 256, 256, 0, stream>>>(packed, gcur, h,
                                                                  nbp, nstride, keys, vals, nbuck, cap);
            sig_kernel8  <<<NPB, 256, 0, stream>>>(h, nbp, nstride, slotarr, keys, vals, n);
            count_rank   <<<NPB, 256, 0, stream>>>(slotarr, vals, f, lrank, partials, n);
            relabel_fused<<<NRB, 512, 0, stream>>>(f, lrank, partials, offsets, it, h, out, n, NPB);
        }
    } else {
        u64* h       = (u64*)p; p += sz_h;
        u64* nb      = (u64*)p; p += sz_h;
        u64* keys    = (u64*)p; p += sz_tblk;
        u32* vals    = (u32*)p; p += sz_tblv;
        u32* slotarr = (u32*)p; p += sz_n4;
        u32* f       = (u32*)p; p += sz_n4;
        u32* lrank   = (u32*)p; p += sz_n4;
        u32* partials= (u32*)p; p += sz_small;
        u32* offsets = (u32*)p;

        argmax_kernel<<<(n + 3) / 4, 256, 0, stream>>>(x, h, out, offsets, n);
        for (int it = 0; it < 3; ++it) {
            init_iter_kernel<<<(TBL_SIZE + 255) / 256, 256, 0, stream>>>(keys, vals, nb, n);
            edge_kernel  <<<4096, 256, 0, stream>>>(src, dst, h, nb, m);
            sig_kernel1  <<<NPB, 256, 0, stream>>>(h, nb, slotarr, keys, vals, n);
            count_rank   <<<NPB, 256, 0, stream>>>(slotarr, vals, f, lrank, partials, n);
            relabel_fused<<<NRB, 512, 0, stream>>>(f, lrank, partials, offsets, it, h, out, n, NPB);
        }
    }
}